// Round 12
// baseline (760.833 us; speedup 1.0000x reference)
//
#include <hip/hip_runtime.h>
#include <hip/hip_bf16.h>

// GraphRNN, fp32 I/O (reference dtypes are float32).
// beta = (seq @ E) / rowsum(graph); agg = graph^T @ beta (per batch);
// Xpre = agg @ Wx + b; then 1024-step scan h = tanh(Xpre_m + h @ Wh).
// MFMA path: fp32 operands split into bf16 hi+lo (rel err ~2^-18).
//
// R23 = R22 + two front restructurings (scan frozen at R15, 622us):
// 1) front1 repacked 1536 -> 448 blocks (one scheduling round at 512
//    resident): beta 256 (unchanged) + weights 64 (8 cols/block) +
//    rowsum 128 (64 rows/block, 8/wave). Same per-element math.
// 2) gemm_agg m-tile 64 -> 128 (grid (8,2,8), acc[2][4]/wave, LDS 64KB,
//    2 blocks/CU): halves betaT HBM re-reads (16 -> 8 MB/batch), doubles
//    per-wave MFMA issue density. Graph-sharing block pairs stay
//    XCD-colocated (delta-bid = 8 == 0 mod 8 -> same L2). Per-output
//    accumulation sequence unchanged -> bit-identical.
// R22's cross-iteration register prefetch kept in all GEMM stagings
// (it was the -24us win: exposed global-load latency now hides under
// the MFMA phase). R21's swz64 LDS swizzle kept.

typedef unsigned short u16;
typedef unsigned int u32;
typedef __bf16 bf16_t;
typedef __bf16 bf16x8 __attribute__((ext_vector_type(8)));
typedef float f32x4 __attribute__((ext_vector_type(4)));
typedef unsigned short u16x8 __attribute__((ext_vector_type(8)));
typedef unsigned short u16x4 __attribute__((ext_vector_type(4)));

#define HP_B  288  // h LDS row pitch (u16) in the scan

struct HiLo { u16 hi, lo; };

__device__ __forceinline__ u16 f2bf(float f) {
  bf16_t h = (bf16_t)f;  // RNE
  return __builtin_bit_cast(u16, h);
}
__device__ __forceinline__ HiLo splitf(float v) {
  bf16_t h = (bf16_t)v;
  HiLo r;
  r.hi = __builtin_bit_cast(u16, h);
  r.lo = f2bf(v - (float)h);
  return r;
}
__device__ __forceinline__ float tanh_fast(float x) {
  float ax = fabsf(x);
  float e  = __expf(-2.0f * ax);
  float t  = __fdividef(1.0f - e, 1.0f + e);
  return copysignf(t, x);
}
// Barrier with LDS-only visibility (drains lgkmcnt, not vmcnt).
__device__ __forceinline__ void sync_lds_only() {
  __asm__ volatile("s_waitcnt lgkmcnt(0)\ns_barrier" ::: "memory");
}
// Swizzled LDS index (u16 units): row pitch 64, 16B-chunk XOR within row.
// Bijective; keeps >=8B-aligned groups contiguous.
__device__ __forceinline__ int swz64(int row, int col) {
  return (row << 6) + (col ^ ((((row >> 2) ^ row) & 7) << 3));
}

// ---------------- K1 front1 (512 thr, 448 blocks = 1 scheduling round) ------
// bid <  256 : raw betaT 64x128 stripe (long poles, dispatched first).
// 256..319   : transpose+split Wx/Wh, 8 columns per block.
// 320..447   : rnorm, 64 rows per block (8 rows per wave).
__global__ __launch_bounds__(512, 2) void front1(
    const float* __restrict__ Wx, u16* __restrict__ Wxth, u16* __restrict__ Wxtl,
    const float* __restrict__ Wh, u16* __restrict__ Whth, u16* __restrict__ Whtl,
    const float* __restrict__ graph, float* __restrict__ rnorm,
    const float* __restrict__ seq, const float* __restrict__ E,
    u16* __restrict__ betaTh, u16* __restrict__ betaTl) {
  __shared__ u16 Ah[64 * 64], Al[64 * 64];
  __shared__ u16 Bh[128 * 64], Bl[128 * 64];
  const int bid = blockIdx.x;
  const int t = threadIdx.x;

  if (bid >= 256 && bid < 320) {  // weight transpose+split, 8 cols/block
    const int wbid = bid - 256;          // 0..63
    const int mat = wbid >> 5;           // 0: Wx, 1: Wh
    const int u0 = (wbid & 31) * 8;
    const float* s; u16 *dh, *dl;
    if (mat == 0) { s = Wx; dh = Wxth; dl = Wxtl; }
    else          { s = Wh; dh = Whth; dl = Whtl; }
#pragma unroll
    for (int jj = 0; jj < 4; jj++) {
      int idx = t + jj * 512;            // 0..2047
      int u = u0 + (idx >> 8), d = idx & 255;
      HiLo r = splitf(s[d * 256 + u]);
      dh[u * 256 + d] = r.hi;
      dl[u * 256 + d] = r.lo;
    }
    return;
  }
  if (bid >= 320) {  // graph row-sums, 64 rows/block (8 per wave)
    const int wave = t >> 6, lane = t & 63;
    const int rbase = (bid - 320) * 64 + wave * 8;
#pragma unroll
    for (int rr = 0; rr < 8; rr++) {
      const int row = rbase + rr;        // 0..8191
      const float* p = graph + (size_t)row * 1024 + lane * 16;
      float s = 0.f;
#pragma unroll
      for (int c = 0; c < 4; c++) {
        f32x4 v = *(const f32x4*)(p + c * 4);
#pragma unroll
        for (int j = 0; j < 4; j++) s += v[j];
      }
#pragma unroll
      for (int off = 32; off > 0; off >>= 1) s += __shfl_xor(s, off);
      if (lane == 0) rnorm[row] = 1.0f / fmaxf(s, 1e-7f);
    }
    return;
  }

  // ---- raw beta (seq @ E): 64 rows x 128 u per block, prefetched ----
  const int v = bid;                          // 0..255
  const int w = t >> 6, lane = t & 63, quad = lane >> 4, l16 = lane & 15;
  const int msub = w & 3, nsub = w >> 2;
  const int r0 = (v >> 1) * 64, n_base = (v & 1) * 128;
  f32x4 acc[4];
#pragma unroll
  for (int i = 0; i < 4; i++) acc[i] = (f32x4){0.f, 0.f, 0.f, 0.f};

  f32x4 rA[2], rB[4];
  // prologue loads, kb = 0
#pragma unroll
  for (int cc = 0; cc < 2; cc++) {
    int c = t + cc * 512;
    int r = c >> 4, c4 = c & 15;
    rA[cc] = *(const f32x4*)(seq + (size_t)(r0 + r) * 256 + c4 * 4);
  }
#pragma unroll
  for (int cc = 0; cc < 4; cc++) {
    int c = t + cc * 512;
    int r = c >> 5, c5 = c & 31;
    rB[cc] = *(const f32x4*)(E + (size_t)r * 256 + n_base + c5 * 4);
  }

  for (int kb = 0; kb < 256; kb += 64) {
    // ---- write phase (regs -> LDS; same values/order as R22) ----
#pragma unroll
    for (int cc = 0; cc < 2; cc++) {  // A: seq rows, split hi/lo
      int c = t + cc * 512;
      int r = c >> 4, c4 = c & 15;
      u16x4 hi, lo;
#pragma unroll
      for (int j = 0; j < 4; j++) {
        HiLo s = splitf(rA[cc][j]);
        hi[j] = s.hi; lo[j] = s.lo;
      }
      *(u16x4*)(Ah + swz64(r, c4 * 4)) = hi;
      *(u16x4*)(Al + swz64(r, c4 * 4)) = lo;
    }
#pragma unroll
    for (int cc = 0; cc < 4; cc++) {  // B: E transposed [u][d]
      int c = t + cc * 512;
      int r = c >> 5, c5 = c & 31;
#pragma unroll
      for (int j = 0; j < 4; j++) {
        HiLo s = splitf(rB[cc][j]);
        Bh[swz64(c5 * 4 + j, r)] = s.hi;
        Bl[swz64(c5 * 4 + j, r)] = s.lo;
      }
    }
    __syncthreads();
    // ---- prefetch next K-tile (overlaps MFMA below) ----
    if (kb + 64 < 256) {
      const int kn = kb + 64;
#pragma unroll
      for (int cc = 0; cc < 2; cc++) {
        int c = t + cc * 512;
        int r = c >> 4, c4 = c & 15;
        rA[cc] = *(const f32x4*)(seq + (size_t)(r0 + r) * 256 + kn + c4 * 4);
      }
#pragma unroll
      for (int cc = 0; cc < 4; cc++) {
        int c = t + cc * 512;
        int r = c >> 5, c5 = c & 31;
        rB[cc] = *(const f32x4*)(E + (size_t)(kn + r) * 256 + n_base + c5 * 4);
      }
    }
    // ---- MFMA phase ----
#pragma unroll
    for (int kk = 0; kk < 64; kk += 32) {
      bf16x8 ah = __builtin_bit_cast(bf16x8, *(const u16x8*)(Ah + swz64(msub * 16 + l16, kk + quad * 8)));
      bf16x8 al = __builtin_bit_cast(bf16x8, *(const u16x8*)(Al + swz64(msub * 16 + l16, kk + quad * 8)));
#pragma unroll
      for (int tN = 0; tN < 4; tN++) {
        int brow = nsub * 64 + tN * 16 + l16;
        bf16x8 bh = __builtin_bit_cast(bf16x8, *(const u16x8*)(Bh + swz64(brow, kk + quad * 8)));
        bf16x8 bl = __builtin_bit_cast(bf16x8, *(const u16x8*)(Bl + swz64(brow, kk + quad * 8)));
        acc[tN] = __builtin_amdgcn_mfma_f32_16x16x32_bf16(ah, bh, acc[tN], 0, 0, 0);
        acc[tN] = __builtin_amdgcn_mfma_f32_16x16x32_bf16(ah, bl, acc[tN], 0, 0, 0);
        acc[tN] = __builtin_amdgcn_mfma_f32_16x16x32_bf16(al, bh, acc[tN], 0, 0, 0);
      }
    }
    __syncthreads();
  }
  const int rbase = r0 + msub * 16 + quad * 4;  // b*1024 + l
  const int bI = rbase >> 10, lI = rbase & 1023;
#pragma unroll
  for (int tN = 0; tN < 4; tN++) {
    int u = n_base + nsub * 64 + tN * 16 + l16;
    u16x4 hv, lv;
#pragma unroll
    for (int i = 0; i < 4; i++) {
      HiLo s = splitf(acc[tN][i]);   // raw beta (rnorm folded into agg)
      hv[i] = s.hi; lv[i] = s.lo;
    }
    size_t off = ((size_t)bI << 18) + (size_t)u * 1024 + lI;
    *(u16x4*)(betaTh + off) = hv;
    *(u16x4*)(betaTl + off) = lv;
  }
}

// ---------------- K2: agg[b][m][u] = sum_l (g[l][m]*rn[l]) * braw[l][u] -----
// 128 m x 128 u per block (grid (8,2,8)); A (graph^T, rn-folded) staged
// once per stripe; betaT reuse doubled vs 64m tiles. Prefetched.
// Waves: msub4 = w&3 (32 m-rows = 2 tiles), nsub2 = w>>2 (64 u).
__global__ __launch_bounds__(512, 2) void gemm_agg(const float* __restrict__ graph,
                                                   const u16* __restrict__ betaTh,
                                                   const u16* __restrict__ betaTl,
                                                   const float* __restrict__ rnorm,
                                                   float* __restrict__ agg) {
  __shared__ u16 Ah[128 * 64], Al[128 * 64];
  __shared__ u16 Bh[128 * 64], Bl[128 * 64];
  const int t = threadIdx.x;
  const int w = t >> 6, lane = t & 63, quad = lane >> 4, l16 = lane & 15;
  const int msub4 = w & 3, nsub2 = w >> 2;
  const int m0 = blockIdx.x * 128, n_base = blockIdx.y * 128, b = blockIdx.z;
  const float* g = graph + (size_t)b * (1024 * 1024);
  const float* rnb = rnorm + b * 1024;
  const size_t bt = (size_t)b << 18;
  f32x4 acc[2][4];
#pragma unroll
  for (int mt = 0; mt < 2; mt++)
#pragma unroll
    for (int i = 0; i < 4; i++) acc[mt][i] = (f32x4){0.f, 0.f, 0.f, 0.f};

  f32x4 rA[4]; float rRn[4]; u16x8 rBh[2], rBl[2];
  // prologue loads, kb = 0  (A: 64 l x 128 m -> 2048 f32x4 / 512 thr = 4)
#pragma unroll
  for (int cc = 0; cc < 4; cc++) {
    int c = t + cc * 512;
    int r = c >> 5, c5 = c & 31;       // r = l_local, c5 = m-chunk of 4
    rA[cc] = *(const f32x4*)(g + (size_t)r * 1024 + m0 + c5 * 4);
    rRn[cc] = rnb[r];
  }
#pragma unroll
  for (int cc = 0; cc < 2; cc++) {
    int c = t + cc * 512;
    int r = c >> 3, c8 = c & 7;
    rBh[cc] = *(const u16x8*)(betaTh + bt + (size_t)(n_base + r) * 1024 + c8 * 8);
    rBl[cc] = *(const u16x8*)(betaTl + bt + (size_t)(n_base + r) * 1024 + c8 * 8);
  }

  for (int kb = 0; kb < 1024; kb += 64) {
    // ---- write phase ----
#pragma unroll
    for (int cc = 0; cc < 4; cc++) {  // A: graph^T * rn (same op order)
      int c = t + cc * 512;
      int r = c >> 5, c5 = c & 31;
#pragma unroll
      for (int j = 0; j < 4; j++) {
        HiLo s = splitf(rA[cc][j] * rRn[cc]);
        Ah[swz64(c5 * 4 + j, r)] = s.hi;  // A[m][l]
        Al[swz64(c5 * 4 + j, r)] = s.lo;
      }
    }
#pragma unroll
    for (int cc = 0; cc < 2; cc++) {  // B: betaT copy
      int c = t + cc * 512;
      int r = c >> 3, c8 = c & 7;
      *(u16x8*)(Bh + swz64(r, c8 * 8)) = rBh[cc];
      *(u16x8*)(Bl + swz64(r, c8 * 8)) = rBl[cc];
    }
    __syncthreads();
    // ---- prefetch next K-tile (overlaps MFMA) ----
    if (kb + 64 < 1024) {
      const int kn = kb + 64;
#pragma unroll
      for (int cc = 0; cc < 4; cc++) {
        int c = t + cc * 512;
        int r = c >> 5, c5 = c & 31;
        rA[cc] = *(const f32x4*)(g + (size_t)(kn + r) * 1024 + m0 + c5 * 4);
        rRn[cc] = rnb[kn + r];
      }
#pragma unroll
      for (int cc = 0; cc < 2; cc++) {
        int c = t + cc * 512;
        int r = c >> 3, c8 = c & 7;
        rBh[cc] = *(const u16x8*)(betaTh + bt + (size_t)(n_base + r) * 1024 + kn + c8 * 8);
        rBl[cc] = *(const u16x8*)(betaTl + bt + (size_t)(n_base + r) * 1024 + kn + c8 * 8);
      }
    }
    // ---- MFMA phase ----
#pragma unroll
    for (int kk = 0; kk < 64; kk += 32) {
#pragma unroll
      for (int mt = 0; mt < 2; mt++) {
        int arow = msub4 * 32 + mt * 16 + l16;
        bf16x8 ah = __builtin_bit_cast(bf16x8, *(const u16x8*)(Ah + swz64(arow, kk + quad * 8)));
        bf16x8 al = __builtin_bit_cast(bf16x8, *(const u16x8*)(Al + swz64(arow, kk + quad * 8)));
#pragma unroll
        for (int tN = 0; tN < 4; tN++) {
          int brow = nsub2 * 64 + tN * 16 + l16;
          bf16x8 bh = __builtin_bit_cast(bf16x8, *(const u16x8*)(Bh + swz64(brow, kk + quad * 8)));
          bf16x8 bl = __builtin_bit_cast(bf16x8, *(const u16x8*)(Bl + swz64(brow, kk + quad * 8)));
          acc[mt][tN] = __builtin_amdgcn_mfma_f32_16x16x32_bf16(ah, bh, acc[mt][tN], 0, 0, 0);
          acc[mt][tN] = __builtin_amdgcn_mfma_f32_16x16x32_bf16(ah, bl, acc[mt][tN], 0, 0, 0);
          acc[mt][tN] = __builtin_amdgcn_mfma_f32_16x16x32_bf16(al, bh, acc[mt][tN], 0, 0, 0);
        }
      }
    }
    __syncthreads();
  }
#pragma unroll
  for (int mt = 0; mt < 2; mt++) {
    const int mbase = m0 + msub4 * 32 + mt * 16 + quad * 4;
#pragma unroll
    for (int tN = 0; tN < 4; tN++) {
      int u = n_base + nsub2 * 64 + tN * 16 + l16;
#pragma unroll
      for (int i = 0; i < 4; i++)
        agg[((size_t)b * 1024 + mbase + i) * 256 + u] = acc[mt][tN][i];
    }
  }
}

// ---------------- K3: Xpre[m][b][u] = (agg @ Wx)[b,m,u] + bias[u] -----------
__global__ __launch_bounds__(512, 2) void gemm_xpre(const float* __restrict__ agg,
                                                    const u16* __restrict__ Wxth,
                                                    const u16* __restrict__ Wxtl,
                                                    const float* __restrict__ bias,
                                                    float* __restrict__ Xpre) {
  __shared__ u16 Ah[64 * 64], Al[64 * 64];
  __shared__ u16 Bh[128 * 64], Bl[128 * 64];
  const int t = threadIdx.x;
  const int w = t >> 6, lane = t & 63, quad = lane >> 4, l16 = lane & 15;
  const int msub = w & 3, nsub = w >> 2;
  const int r0 = blockIdx.x * 64, n_base = blockIdx.y * 128;
  f32x4 acc[4];
#pragma unroll
  for (int i = 0; i < 4; i++) acc[i] = (f32x4){0.f, 0.f, 0.f, 0.f};

  f32x4 rA[2]; u16x8 rBh[2], rBl[2];
  // prologue loads, kb = 0
#pragma unroll
  for (int cc = 0; cc < 2; cc++) {
    int c = t + cc * 512;
    int r = c >> 4, c4 = c & 15;
    rA[cc] = *(const f32x4*)(agg + (size_t)(r0 + r) * 256 + c4 * 4);
  }
#pragma unroll
  for (int cc = 0; cc < 2; cc++) {
    int c = t + cc * 512;
    int r = c >> 3, c8 = c & 7;
    rBh[cc] = *(const u16x8*)(Wxth + (size_t)(n_base + r) * 256 + c8 * 8);
    rBl[cc] = *(const u16x8*)(Wxtl + (size_t)(n_base + r) * 256 + c8 * 8);
  }

  for (int kb = 0; kb < 256; kb += 64) {
    // ---- write phase ----
#pragma unroll
    for (int cc = 0; cc < 2; cc++) {  // A: agg rows, split hi/lo
      int c = t + cc * 512;
      int r = c >> 4, c4 = c & 15;
      u16x4 hi, lo;
#pragma unroll
      for (int j = 0; j < 4; j++) {
        HiLo s = splitf(rA[cc][j]);
        hi[j] = s.hi; lo[j] = s.lo;
      }
      *(u16x4*)(Ah + swz64(r, c4 * 4)) = hi;
      *(u16x4*)(Al + swz64(r, c4 * 4)) = lo;
    }
#pragma unroll
    for (int cc = 0; cc < 2; cc++) {  // B: WxT copy
      int c = t + cc * 512;
      int r = c >> 3, c8 = c & 7;
      *(u16x8*)(Bh + swz64(r, c8 * 8)) = rBh[cc];
      *(u16x8*)(Bl + swz64(r, c8 * 8)) = rBl[cc];
    }
    __syncthreads();
    // ---- prefetch next K-tile (overlaps MFMA) ----
    if (kb + 64 < 256) {
      const int kn = kb + 64;
#pragma unroll
      for (int cc = 0; cc < 2; cc++) {
        int c = t + cc * 512;
        int r = c >> 4, c4 = c & 15;
        rA[cc] = *(const f32x4*)(agg + (size_t)(r0 + r) * 256 + kn + c4 * 4);
      }
#pragma unroll
      for (int cc = 0; cc < 2; cc++) {
        int c = t + cc * 512;
        int r = c >> 3, c8 = c & 7;
        rBh[cc] = *(const u16x8*)(Wxth + (size_t)(n_base + r) * 256 + kn + c8 * 8);
        rBl[cc] = *(const u16x8*)(Wxtl + (size_t)(n_base + r) * 256 + kn + c8 * 8);
      }
    }
    // ---- MFMA phase ----
#pragma unroll
    for (int kk = 0; kk < 64; kk += 32) {
      bf16x8 ah = __builtin_bit_cast(bf16x8, *(const u16x8*)(Ah + swz64(msub * 16 + l16, kk + quad * 8)));
      bf16x8 al = __builtin_bit_cast(bf16x8, *(const u16x8*)(Al + swz64(msub * 16 + l16, kk + quad * 8)));
#pragma unroll
      for (int tN = 0; tN < 4; tN++) {
        int brow = nsub * 64 + tN * 16 + l16;
        bf16x8 bh = __builtin_bit_cast(bf16x8, *(const u16x8*)(Bh + swz64(brow, kk + quad * 8)));
        bf16x8 bl = __builtin_bit_cast(bf16x8, *(const u16x8*)(Bl + swz64(brow, kk + quad * 8)));
        acc[tN] = __builtin_amdgcn_mfma_f32_16x16x32_bf16(ah, bh, acc[tN], 0, 0, 0);
        acc[tN] = __builtin_amdgcn_mfma_f32_16x16x32_bf16(ah, bl, acc[tN], 0, 0, 0);
        acc[tN] = __builtin_amdgcn_mfma_f32_16x16x32_bf16(al, bh, acc[tN], 0, 0, 0);
      }
    }
    __syncthreads();
  }
  const int rbase = r0 + msub * 16 + quad * 4;  // b*1024 + m
  const int bI = rbase >> 10;
#pragma unroll
  for (int tN = 0; tN < 4; tN++) {
    int u = n_base + nsub * 64 + tN * 16 + l16;
    float bu = bias[u];
#pragma unroll
    for (int i = 0; i < 4; i++) {
      int mI = (rbase + i) & 1023;
      Xpre[((size_t)mI * 8 + bI) * 256 + u] = acc[tN][i] + bu;
    }
  }
}

// ---------------- K4: sequential scan — R15 VERBATIM (622us proven) ---------
// 8 WGs (1 batch each), 8 waves. Wave w owns cols [w*32,w*32+32) = 2
// n-tiles. A-tile: 2 rows (h hi/lo), read row clamped to l16&1 ->
// broadcast, conflict-free. Quads 0/1 both hold valid (hi,lo) in C regs
// [0],[1]; quad0 -> tile0, quad1 -> tile1 -> 1 tanh chain/lane. MFMA
// interleave keeps 4 independent accumulator chains (a0a,a1a,a0b,a1b) —
// REQUIRED (R17: 2 chains exposed MFMA latency, +35%). All 8 ds_reads
// hoisted to step top. Nothing precedes MFMA issue (R16 lesson).
__global__ __launch_bounds__(512, 2) void rnn_scan(const u16* __restrict__ Whth,
                                                   const u16* __restrict__ Whtl,
                                                   const float* __restrict__ Xpre,
                                                   float* __restrict__ out) {
  __shared__ u16 h2[2][2 * HP_B];
  const int b = blockIdx.x;
  const int t = threadIdx.x;
  const int w = t >> 6, lane = t & 63, quad = lane >> 4, l16 = lane & 15;
  const int colbase = w * 32;
  const bool epi = (quad < 2);           // quad0 -> tile0, quad1 -> tile1
  const int col_e = colbase + quad * 16 + l16;  // valid for epi lanes

  // Preload Wh hi+lo fragments: 2 n-tiles x 8 k-blocks, hi+lo
  bf16x8 bwh[2][8], bwl[2][8];
#pragma unroll
  for (int tN = 0; tN < 2; tN++) {
    const u16* wph = Whth + (size_t)(colbase + tN * 16 + l16) * 256 + quad * 8;
    const u16* wpl = Whtl + (size_t)(colbase + tN * 16 + l16) * 256 + quad * 8;
#pragma unroll
    for (int kb = 0; kb < 8; kb++) {
      bwh[tN][kb] = __builtin_bit_cast(bf16x8, *(const u16x8*)(wph + kb * 32));
      bwl[tN][kb] = __builtin_bit_cast(bf16x8, *(const u16x8*)(wpl + kb * 32));
    }
  }
  for (int i = t; i < 2 * 2 * HP_B; i += 512) ((u16*)h2)[i] = 0;

  // c banks 0..3: additive input for steps m4+0..m4+3 (epi lanes only).
  float cb[4];
  if (epi) {
#pragma unroll
    for (int k = 0; k < 4; k++) cb[k] = Xpre[(size_t)k * 2048 + b * 256 + col_e];
  }
  // Running pointers (advance by constants; no per-step re-derivation).
  const float* ldp = Xpre + 4 * 2048 + b * 256 + col_e;
  float* outp = out + (size_t)b * 262144 + col_e;
  // Hoisted LDS bases. Read base: row clamped to l16&1 (broadcast dup rows).
  const u16* rb0 = &h2[0][(l16 & 1) * HP_B + quad * 8];
  const u16* rb1 = &h2[1][(l16 & 1) * HP_B + quad * 8];
  u16* wb0 = &h2[0][0];
  u16* wb1 = &h2[1][0];
  __syncthreads();

  for (int m4 = 0; m4 < 1024; m4 += 4) {
#pragma unroll
    for (int k = 0; k < 4; k++) {
      const int p = k & 1;                       // compile-time in unrolled body
      const u16* rb = p ? rb1 : rb0;
      u16* hw = p ? wb0 : wb1;                   // write the other buffer

      // Hoist all 8 A-fragment reads (one lgkmcnt ramp, MFMAs pipeline).
      bf16x8 af[8];
#pragma unroll
      for (int kb = 0; kb < 8; kb++)
        af[kb] = __builtin_bit_cast(bf16x8, *(const u16x8*)(rb + kb * 32));

      f32x4 a0a = {0.f,0.f,0.f,0.f}, a0b = {0.f,0.f,0.f,0.f};
      f32x4 a1a = {0.f,0.f,0.f,0.f}, a1b = {0.f,0.f,0.f,0.f};
#pragma unroll
      for (int kb = 0; kb < 4; kb++) {
        a0a = __builtin_amdgcn_mfma_f32_16x16x32_bf16(af[kb], bwh[0][kb], a0a, 0, 0, 0);
        a1a = __builtin_amdgcn_mfma_f32_16x16x32_bf16(af[kb], bwh[1][kb], a1a, 0, 0, 0);
        a0b = __builtin_amdgcn_mfma_f32_16x16x32_bf16(af[kb + 4], bwh[0][kb + 4], a0b, 0, 0, 0);
        a1b = __builtin_amdgcn_mfma_f32_16x16x32_bf16(af[kb + 4], bwh[1][kb + 4], a1b, 0, 0, 0);
        a0a = __builtin_amdgcn_mfma_f32_16x16x32_bf16(af[kb], bwl[0][kb], a0a, 0, 0, 0);
        a1a = __builtin_amdgcn_mfma_f32_16x16x32_bf16(af[kb], bwl[1][kb], a1a, 0, 0, 0);
        a0b = __builtin_amdgcn_mfma_f32_16x16x32_bf16(af[kb + 4], bwl[0][kb + 4], a0b, 0, 0, 0);
        a1b = __builtin_amdgcn_mfma_f32_16x16x32_bf16(af[kb + 4], bwl[1][kb + 4], a1b, 0, 0, 0);
      }

      // Epilogue distributed: quad0 uses (a0a,a0b), quad1 uses (a1a,a1b).
      if (epi) {
        float sA0 = quad ? a1a[0] : a0a[0];
        float sA1 = quad ? a1a[1] : a0a[1];
        float sB0 = quad ? a1b[0] : a0b[0];
        float sB1 = quad ? a1b[1] : a0b[1];
        float hi_part = sA0 + sB0;
        float lo_part = sA1 + sB1;
        float x = (hi_part + lo_part) + cb[k];
        float y = tanh_fast(x);
        HiLo s = splitf(y);
        hw[col_e] = s.hi;           // row 0 = h_hi
        hw[HP_B + col_e] = s.lo;    // row 1 = h_lo
        *outp = y;                  // fire-and-forget (vmcnt never drained)
        // Prefetch c for step m+4 into the bank just consumed.
        if (m4 <= 1019 - k) {
          cb[k] = *ldp;
          ldp += 2048;
        }
      }
      outp += 256;
      sync_lds_only();
    }
  }
}

extern "C" void kernel_launch(void* const* d_in, const int* in_sizes, int n_in,
                              void* d_out, int out_size, void* d_ws, size_t ws_size,
                              hipStream_t stream) {
  (void)in_sizes; (void)n_in; (void)out_size; (void)ws_size;
  const float* seq   = (const float*)d_in[0];  // (8,1024,256) f32
  const float* graph = (const float*)d_in[1];  // (8,1024,1024) f32
  const float* E     = (const float*)d_in[2];  // (256,256) f32
  const float* Wx    = (const float*)d_in[3];  // (256,256) f32
  const float* Wh    = (const float*)d_in[4];  // (256,256) f32
  const float* bias  = (const float*)d_in[5];  // (256,) f32
  float* out = (float*)d_out;                  // (8,1024,256) f32

  // workspace layout (bytes): ~26 MB total
  char* w = (char*)d_ws;
  float* rnorm  = (float*)(w + 0);          //  32 KB
  u16*   Wxth   = (u16*)(w + 294912);       // 128 KB each
  u16*   Wxtl   = (u16*)(w + 425984);
  u16*   Whth   = (u16*)(w + 557056);
  u16*   Whtl   = (u16*)(w + 688128);
  u16*   betaTh = (u16*)(w + 819200);       // 4 MB [b][u][l] (raw, no rnorm)
  u16*   betaTl = (u16*)(w + 5013504);      // 4 MB
  float* agg    = (float*)(w + 9207808);    // 8 MB [b][m][u]
  float* Xpre   = (float*)(w + 17596416);   // 8 MB [m][b][u]

  front1<<<448, 512, 0, stream>>>(Wx, Wxth, Wxtl, Wh, Whth, Whtl,
                                  graph, rnorm, seq, E, betaTh, betaTl);
  gemm_agg<<<dim3(8, 2, 8), 512, 0, stream>>>(graph, betaTh, betaTl, rnorm, agg);
  gemm_xpre<<<dim3(128, 2), 512, 0, stream>>>(agg, Wxth, Wxtl, bias, Xpre);
  rnn_scan<<<dim3(8), 512, 0, stream>>>(Whth, Whtl, Xpre, out);
}

// Round 13
// 745.299 us; speedup vs baseline: 1.0208x; 1.0208x over previous
//
#include <hip/hip_runtime.h>
#include <hip/hip_bf16.h>

// GraphRNN, fp32 I/O (reference dtypes are float32).
// beta = (seq @ E) / rowsum(graph); agg = graph^T @ beta (per batch);
// Xpre = agg @ Wx + b; then 1024-step scan h = tanh(Xpre_m + h @ Wh).
// MFMA path: fp32 operands split into bf16 hi+lo (rel err ~2^-18).
//
// R24 = R22 wholesale + ONLY R23's front1 repack (448 blocks). R23
// post-mortem: its +13.5us came from the agg m-tile-128 retile — grid
// (8,2,8) = 128 blocks left half the GPU idle and dropped agg to 2
// waves/SIMD (R22's 55KB blocks co-reside 2/CU -> 4 waves/SIMD). Reverted
// to R22's (16,2,8) 64-m agg. front1 repack (one scheduling round:
// beta 256 + weights 64 + rowsum 128) kept to adjudicate it in isolation.
// Scan = R15 verbatim (622us, frozen: R14/R16/R17 all regressed; floor
// model: 256 MFMA/WG/step x ~19.4cy/SIMD = 1242cy vs 1453 measured).
// R22's cross-iteration register prefetch + R21's swz64 swizzle kept.

typedef unsigned short u16;
typedef unsigned int u32;
typedef __bf16 bf16_t;
typedef __bf16 bf16x8 __attribute__((ext_vector_type(8)));
typedef float f32x4 __attribute__((ext_vector_type(4)));
typedef unsigned short u16x8 __attribute__((ext_vector_type(8)));
typedef unsigned short u16x4 __attribute__((ext_vector_type(4)));

#define HP_B  288  // h LDS row pitch (u16) in the scan

struct HiLo { u16 hi, lo; };

__device__ __forceinline__ u16 f2bf(float f) {
  bf16_t h = (bf16_t)f;  // RNE
  return __builtin_bit_cast(u16, h);
}
__device__ __forceinline__ HiLo splitf(float v) {
  bf16_t h = (bf16_t)v;
  HiLo r;
  r.hi = __builtin_bit_cast(u16, h);
  r.lo = f2bf(v - (float)h);
  return r;
}
__device__ __forceinline__ float tanh_fast(float x) {
  float ax = fabsf(x);
  float e  = __expf(-2.0f * ax);
  float t  = __fdividef(1.0f - e, 1.0f + e);
  return copysignf(t, x);
}
// Barrier with LDS-only visibility (drains lgkmcnt, not vmcnt).
__device__ __forceinline__ void sync_lds_only() {
  __asm__ volatile("s_waitcnt lgkmcnt(0)\ns_barrier" ::: "memory");
}
// Swizzled LDS index (u16 units): row pitch 64, 16B-chunk XOR within row.
// Bijective; keeps >=8B-aligned groups contiguous.
__device__ __forceinline__ int swz64(int row, int col) {
  return (row << 6) + (col ^ ((((row >> 2) ^ row) & 7) << 3));
}

// ---------------- K1 front1 (512 thr, 448 blocks = 1 scheduling round) ------
// bid <  256 : raw betaT 64x128 stripe (long poles, dispatched first).
// 256..319   : transpose+split Wx/Wh, 8 columns per block.
// 320..447   : rnorm, 64 rows per block (8 rows per wave).
__global__ __launch_bounds__(512, 2) void front1(
    const float* __restrict__ Wx, u16* __restrict__ Wxth, u16* __restrict__ Wxtl,
    const float* __restrict__ Wh, u16* __restrict__ Whth, u16* __restrict__ Whtl,
    const float* __restrict__ graph, float* __restrict__ rnorm,
    const float* __restrict__ seq, const float* __restrict__ E,
    u16* __restrict__ betaTh, u16* __restrict__ betaTl) {
  __shared__ u16 Ah[64 * 64], Al[64 * 64];
  __shared__ u16 Bh[128 * 64], Bl[128 * 64];
  const int bid = blockIdx.x;
  const int t = threadIdx.x;

  if (bid >= 256 && bid < 320) {  // weight transpose+split, 8 cols/block
    const int wbid = bid - 256;          // 0..63
    const int mat = wbid >> 5;           // 0: Wx, 1: Wh
    const int u0 = (wbid & 31) * 8;
    const float* s; u16 *dh, *dl;
    if (mat == 0) { s = Wx; dh = Wxth; dl = Wxtl; }
    else          { s = Wh; dh = Whth; dl = Whtl; }
#pragma unroll
    for (int jj = 0; jj < 4; jj++) {
      int idx = t + jj * 512;            // 0..2047
      int u = u0 + (idx >> 8), d = idx & 255;
      HiLo r = splitf(s[d * 256 + u]);
      dh[u * 256 + d] = r.hi;
      dl[u * 256 + d] = r.lo;
    }
    return;
  }
  if (bid >= 320) {  // graph row-sums, 64 rows/block (8 per wave)
    const int wave = t >> 6, lane = t & 63;
    const int rbase = (bid - 320) * 64 + wave * 8;
#pragma unroll
    for (int rr = 0; rr < 8; rr++) {
      const int row = rbase + rr;        // 0..8191
      const float* p = graph + (size_t)row * 1024 + lane * 16;
      float s = 0.f;
#pragma unroll
      for (int c = 0; c < 4; c++) {
        f32x4 v = *(const f32x4*)(p + c * 4);
#pragma unroll
        for (int j = 0; j < 4; j++) s += v[j];
      }
#pragma unroll
      for (int off = 32; off > 0; off >>= 1) s += __shfl_xor(s, off);
      if (lane == 0) rnorm[row] = 1.0f / fmaxf(s, 1e-7f);
    }
    return;
  }

  // ---- raw beta (seq @ E): 64 rows x 128 u per block, prefetched ----
  const int v = bid;                          // 0..255
  const int w = t >> 6, lane = t & 63, quad = lane >> 4, l16 = lane & 15;
  const int msub = w & 3, nsub = w >> 2;
  const int r0 = (v >> 1) * 64, n_base = (v & 1) * 128;
  f32x4 acc[4];
#pragma unroll
  for (int i = 0; i < 4; i++) acc[i] = (f32x4){0.f, 0.f, 0.f, 0.f};

  f32x4 rA[2], rB[4];
  // prologue loads, kb = 0
#pragma unroll
  for (int cc = 0; cc < 2; cc++) {
    int c = t + cc * 512;
    int r = c >> 4, c4 = c & 15;
    rA[cc] = *(const f32x4*)(seq + (size_t)(r0 + r) * 256 + c4 * 4);
  }
#pragma unroll
  for (int cc = 0; cc < 4; cc++) {
    int c = t + cc * 512;
    int r = c >> 5, c5 = c & 31;
    rB[cc] = *(const f32x4*)(E + (size_t)r * 256 + n_base + c5 * 4);
  }

  for (int kb = 0; kb < 256; kb += 64) {
    // ---- write phase (regs -> LDS; same values/order as R22) ----
#pragma unroll
    for (int cc = 0; cc < 2; cc++) {  // A: seq rows, split hi/lo
      int c = t + cc * 512;
      int r = c >> 4, c4 = c & 15;
      u16x4 hi, lo;
#pragma unroll
      for (int j = 0; j < 4; j++) {
        HiLo s = splitf(rA[cc][j]);
        hi[j] = s.hi; lo[j] = s.lo;
      }
      *(u16x4*)(Ah + swz64(r, c4 * 4)) = hi;
      *(u16x4*)(Al + swz64(r, c4 * 4)) = lo;
    }
#pragma unroll
    for (int cc = 0; cc < 4; cc++) {  // B: E transposed [u][d]
      int c = t + cc * 512;
      int r = c >> 5, c5 = c & 31;
#pragma unroll
      for (int j = 0; j < 4; j++) {
        HiLo s = splitf(rB[cc][j]);
        Bh[swz64(c5 * 4 + j, r)] = s.hi;
        Bl[swz64(c5 * 4 + j, r)] = s.lo;
      }
    }
    __syncthreads();
    // ---- prefetch next K-tile (overlaps MFMA below) ----
    if (kb + 64 < 256) {
      const int kn = kb + 64;
#pragma unroll
      for (int cc = 0; cc < 2; cc++) {
        int c = t + cc * 512;
        int r = c >> 4, c4 = c & 15;
        rA[cc] = *(const f32x4*)(seq + (size_t)(r0 + r) * 256 + kn + c4 * 4);
      }
#pragma unroll
      for (int cc = 0; cc < 4; cc++) {
        int c = t + cc * 512;
        int r = c >> 5, c5 = c & 31;
        rB[cc] = *(const f32x4*)(E + (size_t)(kn + r) * 256 + n_base + c5 * 4);
      }
    }
    // ---- MFMA phase ----
#pragma unroll
    for (int kk = 0; kk < 64; kk += 32) {
      bf16x8 ah = __builtin_bit_cast(bf16x8, *(const u16x8*)(Ah + swz64(msub * 16 + l16, kk + quad * 8)));
      bf16x8 al = __builtin_bit_cast(bf16x8, *(const u16x8*)(Al + swz64(msub * 16 + l16, kk + quad * 8)));
#pragma unroll
      for (int tN = 0; tN < 4; tN++) {
        int brow = nsub * 64 + tN * 16 + l16;
        bf16x8 bh = __builtin_bit_cast(bf16x8, *(const u16x8*)(Bh + swz64(brow, kk + quad * 8)));
        bf16x8 bl = __builtin_bit_cast(bf16x8, *(const u16x8*)(Bl + swz64(brow, kk + quad * 8)));
        acc[tN] = __builtin_amdgcn_mfma_f32_16x16x32_bf16(ah, bh, acc[tN], 0, 0, 0);
        acc[tN] = __builtin_amdgcn_mfma_f32_16x16x32_bf16(ah, bl, acc[tN], 0, 0, 0);
        acc[tN] = __builtin_amdgcn_mfma_f32_16x16x32_bf16(al, bh, acc[tN], 0, 0, 0);
      }
    }
    __syncthreads();
  }
  const int rbase = r0 + msub * 16 + quad * 4;  // b*1024 + l
  const int bI = rbase >> 10, lI = rbase & 1023;
#pragma unroll
  for (int tN = 0; tN < 4; tN++) {
    int u = n_base + nsub * 64 + tN * 16 + l16;
    u16x4 hv, lv;
#pragma unroll
    for (int i = 0; i < 4; i++) {
      HiLo s = splitf(acc[tN][i]);   // raw beta (rnorm folded into agg)
      hv[i] = s.hi; lv[i] = s.lo;
    }
    size_t off = ((size_t)bI << 18) + (size_t)u * 1024 + lI;
    *(u16x4*)(betaTh + off) = hv;
    *(u16x4*)(betaTl + off) = lv;
  }
}

// ---------------- K2: agg[b][m][u] = sum_l (g[l][m]*rn[l]) * braw[l][u] -----
// 64 m x 128 u per block (grid (16,2,8) = 256 blocks, 2/CU); prefetched.
__global__ __launch_bounds__(512, 2) void gemm_agg(const float* __restrict__ graph,
                                                   const u16* __restrict__ betaTh,
                                                   const u16* __restrict__ betaTl,
                                                   const float* __restrict__ rnorm,
                                                   float* __restrict__ agg) {
  __shared__ u16 Ah[64 * 64], Al[64 * 64];
  __shared__ u16 Bh[128 * 64], Bl[128 * 64];
  const int t = threadIdx.x;
  const int w = t >> 6, lane = t & 63, quad = lane >> 4, l16 = lane & 15;
  const int msub = w & 3, nsub = w >> 2;
  const int m0 = blockIdx.x * 64, n_base = blockIdx.y * 128, b = blockIdx.z;
  const float* g = graph + (size_t)b * (1024 * 1024);
  const float* rnb = rnorm + b * 1024;
  const size_t bt = (size_t)b << 18;
  f32x4 acc[4];
#pragma unroll
  for (int i = 0; i < 4; i++) acc[i] = (f32x4){0.f, 0.f, 0.f, 0.f};

  f32x4 rA[2]; float rRn[2]; u16x8 rBh[2], rBl[2];
  // prologue loads, kb = 0
#pragma unroll
  for (int cc = 0; cc < 2; cc++) {
    int c = t + cc * 512;
    int r = c >> 4, c4 = c & 15;
    rA[cc] = *(const f32x4*)(g + (size_t)r * 1024 + m0 + c4 * 4);
    rRn[cc] = rnb[r];
  }
#pragma unroll
  for (int cc = 0; cc < 2; cc++) {
    int c = t + cc * 512;
    int r = c >> 3, c8 = c & 7;
    rBh[cc] = *(const u16x8*)(betaTh + bt + (size_t)(n_base + r) * 1024 + c8 * 8);
    rBl[cc] = *(const u16x8*)(betaTl + bt + (size_t)(n_base + r) * 1024 + c8 * 8);
  }

  for (int kb = 0; kb < 1024; kb += 64) {
    // ---- write phase ----
#pragma unroll
    for (int cc = 0; cc < 2; cc++) {  // A: graph^T * rn (same op order)
      int c = t + cc * 512;
      int r = c >> 4, c4 = c & 15;
#pragma unroll
      for (int j = 0; j < 4; j++) {
        HiLo s = splitf(rA[cc][j] * rRn[cc]);
        Ah[swz64(c4 * 4 + j, r)] = s.hi;  // A[m][l]
        Al[swz64(c4 * 4 + j, r)] = s.lo;
      }
    }
#pragma unroll
    for (int cc = 0; cc < 2; cc++) {  // B: betaT copy
      int c = t + cc * 512;
      int r = c >> 3, c8 = c & 7;
      *(u16x8*)(Bh + swz64(r, c8 * 8)) = rBh[cc];
      *(u16x8*)(Bl + swz64(r, c8 * 8)) = rBl[cc];
    }
    __syncthreads();
    // ---- prefetch next K-tile (overlaps MFMA) ----
    if (kb + 64 < 1024) {
      const int kn = kb + 64;
#pragma unroll
      for (int cc = 0; cc < 2; cc++) {
        int c = t + cc * 512;
        int r = c >> 4, c4 = c & 15;
        rA[cc] = *(const f32x4*)(g + (size_t)(kn + r) * 1024 + m0 + c4 * 4);
        rRn[cc] = rnb[kn + r];
      }
#pragma unroll
      for (int cc = 0; cc < 2; cc++) {
        int c = t + cc * 512;
        int r = c >> 3, c8 = c & 7;
        rBh[cc] = *(const u16x8*)(betaTh + bt + (size_t)(n_base + r) * 1024 + kn + c8 * 8);
        rBl[cc] = *(const u16x8*)(betaTl + bt + (size_t)(n_base + r) * 1024 + kn + c8 * 8);
      }
    }
    // ---- MFMA phase ----
#pragma unroll
    for (int kk = 0; kk < 64; kk += 32) {
      bf16x8 ah = __builtin_bit_cast(bf16x8, *(const u16x8*)(Ah + swz64(msub * 16 + l16, kk + quad * 8)));
      bf16x8 al = __builtin_bit_cast(bf16x8, *(const u16x8*)(Al + swz64(msub * 16 + l16, kk + quad * 8)));
#pragma unroll
      for (int tN = 0; tN < 4; tN++) {
        int brow = nsub * 64 + tN * 16 + l16;
        bf16x8 bh = __builtin_bit_cast(bf16x8, *(const u16x8*)(Bh + swz64(brow, kk + quad * 8)));
        bf16x8 bl = __builtin_bit_cast(bf16x8, *(const u16x8*)(Bl + swz64(brow, kk + quad * 8)));
        acc[tN] = __builtin_amdgcn_mfma_f32_16x16x32_bf16(ah, bh, acc[tN], 0, 0, 0);
        acc[tN] = __builtin_amdgcn_mfma_f32_16x16x32_bf16(ah, bl, acc[tN], 0, 0, 0);
        acc[tN] = __builtin_amdgcn_mfma_f32_16x16x32_bf16(al, bh, acc[tN], 0, 0, 0);
      }
    }
    __syncthreads();
  }
  const int mbase = m0 + msub * 16 + quad * 4;
#pragma unroll
  for (int tN = 0; tN < 4; tN++) {
    int u = n_base + nsub * 64 + tN * 16 + l16;
#pragma unroll
    for (int i = 0; i < 4; i++)
      agg[((size_t)b * 1024 + mbase + i) * 256 + u] = acc[tN][i];
  }
}

// ---------------- K3: Xpre[m][b][u] = (agg @ Wx)[b,m,u] + bias[u] -----------
__global__ __launch_bounds__(512, 2) void gemm_xpre(const float* __restrict__ agg,
                                                    const u16* __restrict__ Wxth,
                                                    const u16* __restrict__ Wxtl,
                                                    const float* __restrict__ bias,
                                                    float* __restrict__ Xpre) {
  __shared__ u16 Ah[64 * 64], Al[64 * 64];
  __shared__ u16 Bh[128 * 64], Bl[128 * 64];
  const int t = threadIdx.x;
  const int w = t >> 6, lane = t & 63, quad = lane >> 4, l16 = lane & 15;
  const int msub = w & 3, nsub = w >> 2;
  const int r0 = blockIdx.x * 64, n_base = blockIdx.y * 128;
  f32x4 acc[4];
#pragma unroll
  for (int i = 0; i < 4; i++) acc[i] = (f32x4){0.f, 0.f, 0.f, 0.f};

  f32x4 rA[2]; u16x8 rBh[2], rBl[2];
  // prologue loads, kb = 0
#pragma unroll
  for (int cc = 0; cc < 2; cc++) {
    int c = t + cc * 512;
    int r = c >> 4, c4 = c & 15;
    rA[cc] = *(const f32x4*)(agg + (size_t)(r0 + r) * 256 + c4 * 4);
  }
#pragma unroll
  for (int cc = 0; cc < 2; cc++) {
    int c = t + cc * 512;
    int r = c >> 3, c8 = c & 7;
    rBh[cc] = *(const u16x8*)(Wxth + (size_t)(n_base + r) * 256 + c8 * 8);
    rBl[cc] = *(const u16x8*)(Wxtl + (size_t)(n_base + r) * 256 + c8 * 8);
  }

  for (int kb = 0; kb < 256; kb += 64) {
    // ---- write phase ----
#pragma unroll
    for (int cc = 0; cc < 2; cc++) {  // A: agg rows, split hi/lo
      int c = t + cc * 512;
      int r = c >> 4, c4 = c & 15;
      u16x4 hi, lo;
#pragma unroll
      for (int j = 0; j < 4; j++) {
        HiLo s = splitf(rA[cc][j]);
        hi[j] = s.hi; lo[j] = s.lo;
      }
      *(u16x4*)(Ah + swz64(r, c4 * 4)) = hi;
      *(u16x4*)(Al + swz64(r, c4 * 4)) = lo;
    }
#pragma unroll
    for (int cc = 0; cc < 2; cc++) {  // B: WxT copy
      int c = t + cc * 512;
      int r = c >> 3, c8 = c & 7;
      *(u16x8*)(Bh + swz64(r, c8 * 8)) = rBh[cc];
      *(u16x8*)(Bl + swz64(r, c8 * 8)) = rBl[cc];
    }
    __syncthreads();
    // ---- prefetch next K-tile (overlaps MFMA) ----
    if (kb + 64 < 256) {
      const int kn = kb + 64;
#pragma unroll
      for (int cc = 0; cc < 2; cc++) {
        int c = t + cc * 512;
        int r = c >> 4, c4 = c & 15;
        rA[cc] = *(const f32x4*)(agg + (size_t)(r0 + r) * 256 + kn + c4 * 4);
      }
#pragma unroll
      for (int cc = 0; cc < 2; cc++) {
        int c = t + cc * 512;
        int r = c >> 3, c8 = c & 7;
        rBh[cc] = *(const u16x8*)(Wxth + (size_t)(n_base + r) * 256 + kn + c8 * 8);
        rBl[cc] = *(const u16x8*)(Wxtl + (size_t)(n_base + r) * 256 + kn + c8 * 8);
      }
    }
    // ---- MFMA phase ----
#pragma unroll
    for (int kk = 0; kk < 64; kk += 32) {
      bf16x8 ah = __builtin_bit_cast(bf16x8, *(const u16x8*)(Ah + swz64(msub * 16 + l16, kk + quad * 8)));
      bf16x8 al = __builtin_bit_cast(bf16x8, *(const u16x8*)(Al + swz64(msub * 16 + l16, kk + quad * 8)));
#pragma unroll
      for (int tN = 0; tN < 4; tN++) {
        int brow = nsub * 64 + tN * 16 + l16;
        bf16x8 bh = __builtin_bit_cast(bf16x8, *(const u16x8*)(Bh + swz64(brow, kk + quad * 8)));
        bf16x8 bl = __builtin_bit_cast(bf16x8, *(const u16x8*)(Bl + swz64(brow, kk + quad * 8)));
        acc[tN] = __builtin_amdgcn_mfma_f32_16x16x32_bf16(ah, bh, acc[tN], 0, 0, 0);
        acc[tN] = __builtin_amdgcn_mfma_f32_16x16x32_bf16(ah, bl, acc[tN], 0, 0, 0);
        acc[tN] = __builtin_amdgcn_mfma_f32_16x16x32_bf16(al, bh, acc[tN], 0, 0, 0);
      }
    }
    __syncthreads();
  }
  const int rbase = r0 + msub * 16 + quad * 4;  // b*1024 + m
  const int bI = rbase >> 10;
#pragma unroll
  for (int tN = 0; tN < 4; tN++) {
    int u = n_base + nsub * 64 + tN * 16 + l16;
    float bu = bias[u];
#pragma unroll
    for (int i = 0; i < 4; i++) {
      int mI = (rbase + i) & 1023;
      Xpre[((size_t)mI * 8 + bI) * 256 + u] = acc[tN][i] + bu;
    }
  }
}

// ---------------- K4: sequential scan — R15 VERBATIM (622us proven) ---------
// 8 WGs (1 batch each), 8 waves. Wave w owns cols [w*32,w*32+32) = 2
// n-tiles. A-tile: 2 rows (h hi/lo), read row clamped to l16&1 ->
// broadcast, conflict-free. Quads 0/1 both hold valid (hi,lo) in C regs
// [0],[1]; quad0 -> tile0, quad1 -> tile1 -> 1 tanh chain/lane. MFMA
// interleave keeps 4 independent accumulator chains (a0a,a1a,a0b,a1b) —
// REQUIRED (R17: 2 chains exposed MFMA latency, +35%). All 8 ds_reads
// hoisted to step top. Nothing precedes MFMA issue (R16 lesson).
__global__ __launch_bounds__(512, 2) void rnn_scan(const u16* __restrict__ Whth,
                                                   const u16* __restrict__ Whtl,
                                                   const float* __restrict__ Xpre,
                                                   float* __restrict__ out) {
  __shared__ u16 h2[2][2 * HP_B];
  const int b = blockIdx.x;
  const int t = threadIdx.x;
  const int w = t >> 6, lane = t & 63, quad = lane >> 4, l16 = lane & 15;
  const int colbase = w * 32;
  const bool epi = (quad < 2);           // quad0 -> tile0, quad1 -> tile1
  const int col_e = colbase + quad * 16 + l16;  // valid for epi lanes

  // Preload Wh hi+lo fragments: 2 n-tiles x 8 k-blocks, hi+lo
  bf16x8 bwh[2][8], bwl[2][8];
#pragma unroll
  for (int tN = 0; tN < 2; tN++) {
    const u16* wph = Whth + (size_t)(colbase + tN * 16 + l16) * 256 + quad * 8;
    const u16* wpl = Whtl + (size_t)(colbase + tN * 16 + l16) * 256 + quad * 8;
#pragma unroll
    for (int kb = 0; kb < 8; kb++) {
      bwh[tN][kb] = __builtin_bit_cast(bf16x8, *(const u16x8*)(wph + kb * 32));
      bwl[tN][kb] = __builtin_bit_cast(bf16x8, *(const u16x8*)(wpl + kb * 32));
    }
  }
  for (int i = t; i < 2 * 2 * HP_B; i += 512) ((u16*)h2)[i] = 0;

  // c banks 0..3: additive input for steps m4+0..m4+3 (epi lanes only).
  float cb[4];
  if (epi) {
#pragma unroll
    for (int k = 0; k < 4; k++) cb[k] = Xpre[(size_t)k * 2048 + b * 256 + col_e];
  }
  // Running pointers (advance by constants; no per-step re-derivation).
  const float* ldp = Xpre + 4 * 2048 + b * 256 + col_e;
  float* outp = out + (size_t)b * 262144 + col_e;
  // Hoisted LDS bases. Read base: row clamped to l16&1 (broadcast dup rows).
  const u16* rb0 = &h2[0][(l16 & 1) * HP_B + quad * 8];
  const u16* rb1 = &h2[1][(l16 & 1) * HP_B + quad * 8];
  u16* wb0 = &h2[0][0];
  u16* wb1 = &h2[1][0];
  __syncthreads();

  for (int m4 = 0; m4 < 1024; m4 += 4) {
#pragma unroll
    for (int k = 0; k < 4; k++) {
      const int p = k & 1;                       // compile-time in unrolled body
      const u16* rb = p ? rb1 : rb0;
      u16* hw = p ? wb0 : wb1;                   // write the other buffer

      // Hoist all 8 A-fragment reads (one lgkmcnt ramp, MFMAs pipeline).
      bf16x8 af[8];
#pragma unroll
      for (int kb = 0; kb < 8; kb++)
        af[kb] = __builtin_bit_cast(bf16x8, *(const u16x8*)(rb + kb * 32));

      f32x4 a0a = {0.f,0.f,0.f,0.f}, a0b = {0.f,0.f,0.f,0.f};
      f32x4 a1a = {0.f,0.f,0.f,0.f}, a1b = {0.f,0.f,0.f,0.f};
#pragma unroll
      for (int kb = 0; kb < 4; kb++) {
        a0a = __builtin_amdgcn_mfma_f32_16x16x32_bf16(af[kb], bwh[0][kb], a0a, 0, 0, 0);
        a1a = __builtin_amdgcn_mfma_f32_16x16x32_bf16(af[kb], bwh[1][kb], a1a, 0, 0, 0);
        a0b = __builtin_amdgcn_mfma_f32_16x16x32_bf16(af[kb + 4], bwh[0][kb + 4], a0b, 0, 0, 0);
        a1b = __builtin_amdgcn_mfma_f32_16x16x32_bf16(af[kb + 4], bwh[1][kb + 4], a1b, 0, 0, 0);
        a0a = __builtin_amdgcn_mfma_f32_16x16x32_bf16(af[kb], bwl[0][kb], a0a, 0, 0, 0);
        a1a = __builtin_amdgcn_mfma_f32_16x16x32_bf16(af[kb], bwl[1][kb], a1a, 0, 0, 0);
        a0b = __builtin_amdgcn_mfma_f32_16x16x32_bf16(af[kb + 4], bwl[0][kb + 4], a0b, 0, 0, 0);
        a1b = __builtin_amdgcn_mfma_f32_16x16x32_bf16(af[kb + 4], bwl[1][kb + 4], a1b, 0, 0, 0);
      }

      // Epilogue distributed: quad0 uses (a0a,a0b), quad1 uses (a1a,a1b).
      if (epi) {
        float sA0 = quad ? a1a[0] : a0a[0];
        float sA1 = quad ? a1a[1] : a0a[1];
        float sB0 = quad ? a1b[0] : a0b[0];
        float sB1 = quad ? a1b[1] : a0b[1];
        float hi_part = sA0 + sB0;
        float lo_part = sA1 + sB1;
        float x = (hi_part + lo_part) + cb[k];
        float y = tanh_fast(x);
        HiLo s = splitf(y);
        hw[col_e] = s.hi;           // row 0 = h_hi
        hw[HP_B + col_e] = s.lo;    // row 1 = h_lo
        *outp = y;                  // fire-and-forget (vmcnt never drained)
        // Prefetch c for step m+4 into the bank just consumed.
        if (m4 <= 1019 - k) {
          cb[k] = *ldp;
          ldp += 2048;
        }
      }
      outp += 256;
      sync_lds_only();
    }
  }
}

extern "C" void kernel_launch(void* const* d_in, const int* in_sizes, int n_in,
                              void* d_out, int out_size, void* d_ws, size_t ws_size,
                              hipStream_t stream) {
  (void)in_sizes; (void)n_in; (void)out_size; (void)ws_size;
  const float* seq   = (const float*)d_in[0];  // (8,1024,256) f32
  const float* graph = (const float*)d_in[1];  // (8,1024,1024) f32
  const float* E     = (const float*)d_in[2];  // (256,256) f32
  const float* Wx    = (const float*)d_in[3];  // (256,256) f32
  const float* Wh    = (const float*)d_in[4];  // (256,256) f32
  const float* bias  = (const float*)d_in[5];  // (256,) f32
  float* out = (float*)d_out;                  // (8,1024,256) f32

  // workspace layout (bytes): ~26 MB total
  char* w = (char*)d_ws;
  float* rnorm  = (float*)(w + 0);          //  32 KB
  u16*   Wxth   = (u16*)(w + 294912);       // 128 KB each
  u16*   Wxtl   = (u16*)(w + 425984);
  u16*   Whth   = (u16*)(w + 557056);
  u16*   Whtl   = (u16*)(w + 688128);
  u16*   betaTh = (u16*)(w + 819200);       // 4 MB [b][u][l] (raw, no rnorm)
  u16*   betaTl = (u16*)(w + 5013504);      // 4 MB
  float* agg    = (float*)(w + 9207808);    // 8 MB [b][m][u]
  float* Xpre   = (float*)(w + 17596416);   // 8 MB [m][b][u]

  front1<<<448, 512, 0, stream>>>(Wx, Wxth, Wxtl, Wh, Whth, Whtl,
                                  graph, rnorm, seq, E, betaTh, betaTl);
  gemm_agg<<<dim3(16, 2, 8), 512, 0, stream>>>(graph, betaTh, betaTl, rnorm, agg);
  gemm_xpre<<<dim3(128, 2), 512, 0, stream>>>(agg, Wxth, Wxtl, bias, Xpre);
  rnn_scan<<<dim3(8), 512, 0, stream>>>(Whth, Whtl, Xpre, out);
}